// Round 1
// baseline (2523.068 us; speedup 1.0000x reference)
//
#include <hip/hip_runtime.h>
#include <math.h>

#define N_NODES 131072
#define N_EDGES 2097152
#define S_SEG   512
#define F_INPUT 64
#define HID     128
#define EMB     128
#define RNN_HID 256

// ---------------------------------------------------------------------------
// Graph preprocessing: counts + weighted degree
// ---------------------------------------------------------------------------
__global__ void zero_kernel(int* __restrict__ cnt, float* __restrict__ degw, int n) {
    int i = blockIdx.x * blockDim.x + threadIdx.x;
    if (i < n) { cnt[i] = 0; degw[i] = 0.f; }
}

__global__ void count_kernel(const int* __restrict__ dst, const float* __restrict__ ew,
                             int* __restrict__ cnt, float* __restrict__ degw, int e) {
    int i = blockIdx.x * blockDim.x + threadIdx.x;
    if (i < e) {
        int d = dst[i];
        atomicAdd(&cnt[d], 1);
        atomicAdd(&degw[d], ew[i]);
    }
}

// exclusive scan of cnt[n] -> row_ptr[n+1]; cnt becomes cursor (copy of row_ptr)
__global__ __launch_bounds__(1024) void scan_kernel(int* __restrict__ cnt,
                                                    int* __restrict__ row_ptr, int n) {
    __shared__ int sums[1024];
    int tid = threadIdx.x;
    int per = n / 1024;            // 128
    int base = tid * per;
    int s = 0;
    for (int k = 0; k < per; k++) s += cnt[base + k];
    sums[tid] = s;
    __syncthreads();
    for (int off = 1; off < 1024; off <<= 1) {
        int v = (tid >= off) ? sums[tid - off] : 0;
        __syncthreads();
        sums[tid] += v;
        __syncthreads();
    }
    int run = (tid > 0) ? sums[tid - 1] : 0;
    for (int k = 0; k < per; k++) {
        int v = cnt[base + k];
        row_ptr[base + k] = run;
        cnt[base + k] = run;       // cursor
        run += v;
    }
    if (tid == 1023) row_ptr[n] = run;
}

__global__ void dinv_kernel(const float* __restrict__ degw, float* __restrict__ dinv, int n) {
    int i = blockIdx.x * blockDim.x + threadIdx.x;
    if (i < n) dinv[i] = rsqrtf(degw[i] + 1.0f);   // +1 = self-loop weight; deg >= 1 always
}

__global__ void scatter_kernel(const int* __restrict__ src, const int* __restrict__ dst,
                               const float* __restrict__ ew, int* __restrict__ cursor,
                               int* __restrict__ col, float* __restrict__ wv, int e) {
    int i = blockIdx.x * blockDim.x + threadIdx.x;
    if (i < e) {
        int d = dst[i];
        int p = atomicAdd(&cursor[d], 1);
        col[p] = src[i];
        wv[p]  = ew[i];
    }
}

// ---------------------------------------------------------------------------
// Dense GEMM: Y[M x 128] = X[M x K] @ W[K x 128], K in {64,128}, M % 64 == 0
// block = 256 threads, tile 64 rows x 128 cols, micro-tile 8x4
// ---------------------------------------------------------------------------
__global__ __launch_bounds__(256) void gemm_kernel(const float* __restrict__ X,
                                                   const float* __restrict__ W,
                                                   float* __restrict__ Y, int K) {
    __shared__ float Xs[64][68];   // [k][m], padded for alignment/banks
    __shared__ float Ws[64][128];  // [k][n]
    int tid = threadIdx.x;
    int m0 = blockIdx.x * 64;
    int tr = tid >> 5;             // 0..7
    int tc = tid & 31;             // 0..31
    int r0 = tr * 8;
    int c0 = tc * 4;
    float acc[8][4];
#pragma unroll
    for (int i = 0; i < 8; i++)
#pragma unroll
        for (int j = 0; j < 4; j++) acc[i][j] = 0.f;

    for (int kt = 0; kt < K; kt += 64) {
        // stage X tile (64 rows x 64 k), transposed into Xs[k][m]
#pragma unroll
        for (int i = 0; i < 4; i++) {
            int lin = i * 256 + tid;       // float4 id in [0,1024)
            int row = lin >> 4;
            int kq  = lin & 15;
            float4 v = *(const float4*)&X[(size_t)(m0 + row) * K + kt + kq * 4];
            Xs[kq * 4 + 0][row] = v.x;
            Xs[kq * 4 + 1][row] = v.y;
            Xs[kq * 4 + 2][row] = v.z;
            Xs[kq * 4 + 3][row] = v.w;
        }
        // stage W tile (64 k x 128 n)
#pragma unroll
        for (int i = 0; i < 8; i++) {
            int lin = i * 256 + tid;       // float4 id in [0,2048)
            int kk = lin >> 5;
            int cq = lin & 31;
            *(float4*)&Ws[kk][cq * 4] = *(const float4*)&W[(size_t)(kt + kk) * 128 + cq * 4];
        }
        __syncthreads();
#pragma unroll
        for (int k = 0; k < 64; k++) {
            float4 b  = *(const float4*)&Ws[k][c0];
            float4 a0 = *(const float4*)&Xs[k][r0];
            float4 a1 = *(const float4*)&Xs[k][r0 + 4];
            float a[8] = {a0.x, a0.y, a0.z, a0.w, a1.x, a1.y, a1.z, a1.w};
            float bb[4] = {b.x, b.y, b.z, b.w};
#pragma unroll
            for (int i = 0; i < 8; i++)
#pragma unroll
                for (int j = 0; j < 4; j++) acc[i][j] += a[i] * bb[j];
        }
        __syncthreads();
    }
#pragma unroll
    for (int i = 0; i < 8; i++) {
        float4 v = make_float4(acc[i][0], acc[i][1], acc[i][2], acc[i][3]);
        *(float4*)&Y[(size_t)(m0 + r0 + i) * 128 + c0] = v;
    }
}

// ---------------------------------------------------------------------------
// SpMM: out[i][:] = relu( dinv[i]^2 * t[i][:] + sum_e dinv[i]*w_e*dinv[col_e] * t[col_e][:] + bias )
// one wave per node, lane handles 2 features (float2)
// ---------------------------------------------------------------------------
__global__ __launch_bounds__(256) void spmm_kernel(const float* __restrict__ t,
                                                   const int* __restrict__ row_ptr,
                                                   const int* __restrict__ col,
                                                   const float* __restrict__ wv,
                                                   const float* __restrict__ dinv,
                                                   const float* __restrict__ bias,
                                                   float* __restrict__ out) {
    int wave = threadIdx.x >> 6;
    int lane = threadIdx.x & 63;
    int i = blockIdx.x * 4 + wave;
    int f = lane * 2;
    float di = dinv[i];
    float2 self = *(const float2*)&t[(size_t)i * HID + f];
    float sc = di * di;
    float ax = sc * self.x, ay = sc * self.y;
    int p0 = row_ptr[i], p1 = row_ptr[i + 1];
    for (int p = p0; p < p1; p++) {
        int c = col[p];
        float coef = di * wv[p] * dinv[c];
        float2 v = *(const float2*)&t[(size_t)c * HID + f];
        ax += coef * v.x;
        ay += coef * v.y;
    }
    float2 b = *(const float2*)&bias[f];
    ax = fmaxf(ax + b.x, 0.f);
    ay = fmaxf(ay + b.y, 0.f);
    float2 r; r.x = ax; r.y = ay;
    *(float2*)&out[(size_t)i * HID + f] = r;
}

// ---------------------------------------------------------------------------
// Segment starts via binary search on sorted batch
// ---------------------------------------------------------------------------
__global__ void segstart_kernel(const int* __restrict__ batch, int* __restrict__ seg, int n) {
    int s = blockIdx.x * blockDim.x + threadIdx.x;
    if (s <= S_SEG) {
        int lo = 0, hi = n;
        while (lo < hi) {
            int m = (lo + hi) >> 1;
            if (batch[m] < s) lo = m + 1; else hi = m;
        }
        seg[s] = lo;
    }
}

__global__ __launch_bounds__(128) void pool_kernel(const float* __restrict__ z,
                                                   const int* __restrict__ seg,
                                                   float* __restrict__ pooled) {
    int s = blockIdx.x;
    int fidx = threadIdx.x;
    int a = seg[s], b = seg[s + 1];
    float sum = 0.f;
    for (int r = a; r < b; r++) sum += z[(size_t)r * HID + fidx];
    float cnt = (float)(b - a);
    pooled[(size_t)s * EMB + fidx] = sum / fmaxf(cnt, 1.f);
}

// ---------------------------------------------------------------------------
// tanh RNN: 1 block, 512 threads; thread pair (j, half) owns output j,
// weights register-resident, x/h broadcast through LDS
// ---------------------------------------------------------------------------
__global__ __launch_bounds__(512, 2) void rnn_kernel(const float* __restrict__ pooled,
                                                     const float* __restrict__ Wih,
                                                     const float* __restrict__ Whh,
                                                     const float* __restrict__ bih,
                                                     const float* __restrict__ bhh,
                                                     float* __restrict__ hs) {
    __shared__ float xs[EMB];
    __shared__ float hb[RNN_HID];
    int tid = threadIdx.x;
    int j = tid >> 1, half = tid & 1;

    float wih[64];
    float whh[128];
    const float* wb = Wih + (size_t)j * EMB + half * 64;
#pragma unroll
    for (int q = 0; q < 16; q++) {
        float4 v = *(const float4*)&wb[q * 4];
        wih[4 * q] = v.x; wih[4 * q + 1] = v.y; wih[4 * q + 2] = v.z; wih[4 * q + 3] = v.w;
    }
    const float* hbp = Whh + (size_t)j * RNN_HID + half * 128;
#pragma unroll
    for (int q = 0; q < 32; q++) {
        float4 v = *(const float4*)&hbp[q * 4];
        whh[4 * q] = v.x; whh[4 * q + 1] = v.y; whh[4 * q + 2] = v.z; whh[4 * q + 3] = v.w;
    }
    float bsum = (half == 0) ? (bih[j] + bhh[j]) : 0.f;

    if (tid < RNN_HID) hb[tid] = 0.f;
    __syncthreads();

    for (int t = 0; t < S_SEG; t++) {
        if (tid < EMB) xs[tid] = pooled[(size_t)t * EMB + tid];
        __syncthreads();
        float acc = 0.f;
        const float4* xv = (const float4*)&xs[half * 64];
#pragma unroll
        for (int q = 0; q < 16; q++) {
            float4 v = xv[q];
            acc += wih[4 * q] * v.x + wih[4 * q + 1] * v.y
                 + wih[4 * q + 2] * v.z + wih[4 * q + 3] * v.w;
        }
        const float4* hv = (const float4*)&hb[half * 128];
#pragma unroll
        for (int q = 0; q < 32; q++) {
            float4 v = hv[q];
            acc += whh[4 * q] * v.x + whh[4 * q + 1] * v.y
                 + whh[4 * q + 2] * v.z + whh[4 * q + 3] * v.w;
        }
        float other = __shfl_xor(acc, 1, 64);
        float hn = 0.f;
        if (half == 0) hn = tanhf(acc + other + bsum);
        __syncthreads();           // all reads of hb/xs for step t done
        if (half == 0) {
            hb[j] = hn;
            hs[(size_t)t * RNN_HID + j] = hn;
        }
    }
}

// ---------------------------------------------------------------------------
// Final linear + sigmoid: one wave per sequence position
// ---------------------------------------------------------------------------
__global__ __launch_bounds__(256) void logits_kernel(const float* __restrict__ hs,
                                                     const float* __restrict__ Wl,
                                                     const float* __restrict__ bl,
                                                     float* __restrict__ out) {
    int tid = threadIdx.x;
    int wave = tid >> 6, lane = tid & 63;
    int s = blockIdx.x * 4 + wave;
    float4 h = ((const float4*)&hs[(size_t)s * RNN_HID])[lane];
    float4 w0 = ((const float4*)Wl)[lane];
    float4 w1 = ((const float4*)(Wl + RNN_HID))[lane];
    float a0 = h.x * w0.x + h.y * w0.y + h.z * w0.z + h.w * w0.w;
    float a1 = h.x * w1.x + h.y * w1.y + h.z * w1.z + h.w * w1.w;
#pragma unroll
    for (int off = 32; off; off >>= 1) {
        a0 += __shfl_xor(a0, off, 64);
        a1 += __shfl_xor(a1, off, 64);
    }
    if (lane == 0) {
        out[s * 2 + 0] = 1.f / (1.f + expf(-(a0 + bl[0])));
        out[s * 2 + 1] = 1.f / (1.f + expf(-(a1 + bl[1])));
    }
}

// ---------------------------------------------------------------------------
extern "C" void kernel_launch(void* const* d_in, const int* in_sizes, int n_in,
                              void* d_out, int out_size, void* d_ws, size_t ws_size,
                              hipStream_t stream) {
    const float* x    = (const float*)d_in[0];
    const float* ew   = (const float*)d_in[1];
    const int*   src  = (const int*)d_in[2];
    const int*   dst  = (const int*)d_in[3];
    const int*   batch= (const int*)d_in[4];
    const float* W1   = (const float*)d_in[5];
    const float* b1   = (const float*)d_in[6];
    const float* W2   = (const float*)d_in[7];
    const float* b2   = (const float*)d_in[8];
    const float* W3   = (const float*)d_in[9];
    const float* b3   = (const float*)d_in[10];
    const float* Wih  = (const float*)d_in[11];
    const float* Whh  = (const float*)d_in[12];
    const float* bih  = (const float*)d_in[13];
    const float* bhh  = (const float*)d_in[14];
    const float* Wl   = (const float*)d_in[15];
    const float* bl   = (const float*)d_in[16];
    float* out = (float*)d_out;
    (void)in_sizes; (void)n_in; (void)out_size; (void)ws_size;

    char* ws = (char*)d_ws;
    size_t o = 0;
    auto alloc = [&](size_t bytes) -> char* {
        o = (o + 255) & ~(size_t)255;
        char* p = ws + o;
        o += bytes;
        return p;
    };
    float* bufA   = (float*)alloc((size_t)N_NODES * HID * 4);
    float* bufB   = (float*)alloc((size_t)N_NODES * HID * 4);
    int*   colA   = (int*)  alloc((size_t)N_EDGES * 4);
    float* wvA    = (float*)alloc((size_t)N_EDGES * 4);
    int*   rowp   = (int*)  alloc((size_t)(N_NODES + 1) * 4);
    int*   cursor = (int*)  alloc((size_t)N_NODES * 4);
    float* degw   = (float*)alloc((size_t)N_NODES * 4);
    float* dinv   = (float*)alloc((size_t)N_NODES * 4);
    int*   seg    = (int*)  alloc((size_t)(S_SEG + 1) * 4);
    float* pooled = (float*)alloc((size_t)S_SEG * EMB * 4);
    float* hs     = (float*)alloc((size_t)S_SEG * RNN_HID * 4);

    // --- CSR build ---
    zero_kernel<<<(N_NODES + 255) / 256, 256, 0, stream>>>(cursor, degw, N_NODES);
    count_kernel<<<(N_EDGES + 255) / 256, 256, 0, stream>>>(dst, ew, cursor, degw, N_EDGES);
    scan_kernel<<<1, 1024, 0, stream>>>(cursor, rowp, N_NODES);
    dinv_kernel<<<(N_NODES + 255) / 256, 256, 0, stream>>>(degw, dinv, N_NODES);
    scatter_kernel<<<(N_EDGES + 255) / 256, 256, 0, stream>>>(src, dst, ew, cursor, colA, wvA, N_EDGES);

    // --- GCN layer 1: t = x@W1 ; h = relu(spmm(t)+b1) ---
    gemm_kernel<<<N_NODES / 64, 256, 0, stream>>>(x, W1, bufA, F_INPUT);
    spmm_kernel<<<N_NODES / 4, 256, 0, stream>>>(bufA, rowp, colA, wvA, dinv, b1, bufB);
    // --- layer 2 ---
    gemm_kernel<<<N_NODES / 64, 256, 0, stream>>>(bufB, W2, bufA, HID);
    spmm_kernel<<<N_NODES / 4, 256, 0, stream>>>(bufA, rowp, colA, wvA, dinv, b2, bufB);
    // --- layer 3 (final relu fused: pooling consumes relu(h3)) ---
    gemm_kernel<<<N_NODES / 64, 256, 0, stream>>>(bufB, W3, bufA, HID);
    spmm_kernel<<<N_NODES / 4, 256, 0, stream>>>(bufA, rowp, colA, wvA, dinv, b3, bufB);

    // --- mean pool per subgraph ---
    segstart_kernel<<<(S_SEG + 1 + 255) / 256, 256, 0, stream>>>(batch, seg, N_NODES);
    pool_kernel<<<S_SEG, 128, 0, stream>>>(bufB, seg, pooled);

    // --- RNN + head ---
    rnn_kernel<<<1, 512, 0, stream>>>(pooled, Wih, Whh, bih, bhh, hs);
    logits_kernel<<<S_SEG / 4, 256, 0, stream>>>(hs, Wl, bl, out);
}